// Round 17
// baseline (1095.498 us; speedup 1.0000x reference)
//
#include <hip/hip_runtime.h>
#include <math.h>

#define N_NODES 50000
#define E_EDGES 1600000
#define F_IN    2000
#define D       20
#define NCOL    160   // 2 edge types * [q s k v] * 20
#define KPAD    2016  // 63 * 32
#define NBNP    64    // BN partial slots
#define LSTR    40    // LDS row stride in bf16 (80B)

#define INV_SQRT_D 0.22360679774997896f

typedef __bf16 bf16x8 __attribute__((ext_vector_type(8)));
typedef __bf16 bf16x4 __attribute__((ext_vector_type(4)));
typedef float  f32x4  __attribute__((ext_vector_type(4)));

// Layouts:
//   QS[node][et*40 + mat*20 + d]  (mat 0=q,1=s), 160B rows
//   KV[et][node*64 + mat2*20 + d] (mat2 0=k,1=v), 128B-aligned rows, k+v in first 80B

// ---------------- pack weights + zero accumulators --------------------------------------
__global__ void pack_kernel(
    const float* __restrict__ W0q, const float* __restrict__ W0k,
    const float* __restrict__ W0v, const float* __restrict__ W0s,
    const float* __restrict__ b0q, const float* __restrict__ b0k,
    const float* __restrict__ b0v, const float* __restrict__ b0s,
    const float* __restrict__ Wq,  const float* __restrict__ Wk,
    const float* __restrict__ Wv,  const float* __restrict__ Ws_,
    const float* __restrict__ bq,  const float* __restrict__ bk,
    const float* __restrict__ bv,  const float* __restrict__ bs_,
    __bf16* __restrict__ B0, float* __restrict__ bias0,
    float* __restrict__ WL, float* __restrict__ biasL,
    float* __restrict__ bnp, int* __restrict__ deg)
{
  long idx = (long)blockIdx.x * blockDim.x + threadIdx.x;
  if (idx < (long)NCOL*KPAD) {              // B0T: [160][2016] bf16
    int col = (int)(idx / KPAD), k = (int)(idx % KPAD);
    int et = col / 80, r = col % 80, mat = r / 20, d = r % 20;
    const float* w = (mat==0)?W0q:(mat==1)?W0s:(mat==2)?W0k:W0v;
    float v = (k < F_IN) ? w[((size_t)et*F_IN + k)*D + d] : 0.f;
    B0[idx] = (__bf16)v;
    return;
  }
  idx -= (long)NCOL*KPAD;
  if (idx < 160) {                          // bias0
    int col = (int)idx;
    int et = col / 80, r = col % 80, mat = r / 20, d = r % 20;
    const float* b = (mat==0)?b0q:(mat==1)?b0s:(mat==2)?b0k:b0v;
    bias0[col] = b[et*D + d];
    return;
  }
  idx -= 160;
  if (idx < 9600) {                         // WL: 3 x [20][160]
    int l = (int)(idx / 3200), rem = (int)(idx % 3200);
    int k = rem / NCOL, col = rem % NCOL;
    int et = col / 80, r = col % 80, mat = r / 20, d = r % 20;
    const float* w = (mat==0)?Wq:(mat==1)?Ws_:(mat==2)?Wk:Wv;
    WL[idx] = w[(((size_t)l*2 + et)*D + k)*D + d];
    return;
  }
  idx -= 9600;
  if (idx < 480) {                          // biasL: 3 x [160]
    int l = (int)(idx / NCOL), col = (int)(idx % NCOL);
    int et = col / 80, r = col % 80, mat = r / 20, d = r % 20;
    const float* b = (mat==0)?bq:(mat==1)?bs_:(mat==2)?bk:bv;
    biasL[idx] = b[(l*2 + et)*D + d];
    return;
  }
  idx -= 480;
  if (idx < 4*NBNP*40) { bnp[idx] = 0.f; return; } // BN partials: [4][64][40]
  idx -= 4*NBNP*40;
  if (idx < 2*N_NODES) { deg[idx] = 0; return; }
}

// ---------------- CSR build (XCD-partitioned) --------------------------------------------
#define SC_EPT 16
#define SC_CHUNK (256*SC_EPT)

__global__ void hist_kernel(const int* __restrict__ same, const int* __restrict__ diff,
                            int* __restrict__ deg)
{
  const int part  = blockIdx.x & 7;
  const int chunk = blockIdx.x >> 3;
  const int lo = part * (N_NODES/8);
  const int hi = lo + (N_NODES/8);
  const long i0 = (long)chunk * SC_CHUNK + threadIdx.x;
#pragma unroll
  for (int it = 0; it < SC_EPT; ++it) {
    long i = i0 + (long)it*256;
    if (i >= 2L*E_EDGES) break;
    int et = (i >= E_EDGES) ? 1 : 0;
    long e = i - (long)et*E_EDGES;
    const int* ix = et ? diff : same;
    int dst = ix[E_EDGES + e];
    if (dst >= lo && dst < hi)
      atomicAdd(&deg[(size_t)et*N_NODES + dst], 1);
  }
}

__global__ void scan_kernel(const int* __restrict__ deg,
                            int* __restrict__ rowptr0, int* __restrict__ rowptr1,
                            int* __restrict__ next0, int* __restrict__ next1)
{
  const int et = blockIdx.x;
  const int* dg = deg + (size_t)et*N_NODES;
  int* rp = et ? rowptr1 : rowptr0;
  int* np = et ? next1 : next0;
  __shared__ int part[1024];
  const int t = threadIdx.x;
  const int per = (N_NODES + 1023) / 1024;  // 49
  const int b = t * per;
  const int e = (b + per < N_NODES) ? (b + per) : N_NODES;
  int s = 0;
  for (int i = b; i < e; i++) s += dg[i];
  part[t] = s;
  __syncthreads();
  for (int o = 1; o < 1024; o <<= 1) {
    int v = (t >= o) ? part[t-o] : 0;
    __syncthreads();
    part[t] += v;
    __syncthreads();
  }
  int run = (t == 0) ? 0 : part[t-1];
  for (int i = b; i < e; i++) {
    rp[i] = run; np[i] = run;
    run += dg[i];
  }
  if (t == 0) rp[N_NODES] = part[1023];
}

__global__ void scatter_kernel(const int* __restrict__ same, const int* __restrict__ diff,
                               int* __restrict__ next0, int* __restrict__ next1,
                               int* __restrict__ adj0, int* __restrict__ adj1)
{
  const int part  = blockIdx.x & 7;
  const int chunk = blockIdx.x >> 3;
  const int lo = part * (N_NODES/8);
  const int hi = lo + (N_NODES/8);
  const long i0 = (long)chunk * SC_CHUNK + threadIdx.x;
#pragma unroll
  for (int it = 0; it < SC_EPT; ++it) {
    long i = i0 + (long)it*256;
    if (i >= 2L*E_EDGES) break;
    int et = (i >= E_EDGES) ? 1 : 0;
    long e = i - (long)et*E_EDGES;
    const int* ix = et ? diff : same;
    int dst = ix[E_EDGES + e];
    if (dst >= lo && dst < hi) {
      int src = ix[e];
      int* np  = et ? next1 : next0;
      int* adj = et ? adj1  : adj0;
      int pos = atomicAdd(&np[dst], 1);
      adj[pos] = src;
    }
  }
}

// ---------------- layer-0 MFMA GEMM: 32-row tiles, 128 threads, 1563 blocks -------------
// 2 waves per block (each 80 cols, 2x5 frags over the same 32 rows); depth-2 LDS dbuf.
// 2x the blocks of the 64-row version -> 2x resident waves to hide HBM latency.
__launch_bounds__(128)
__global__ void gemm0_mfma(const float* __restrict__ A,
                           const __bf16* __restrict__ Bt,
                           const float* __restrict__ bias,
                           __bf16* __restrict__ QS,
                           __bf16* __restrict__ KV0, __bf16* __restrict__ KV1)
{
  __shared__ __bf16 as[2][32*LSTR];
  const int t    = threadIdx.x;
  const int lane = t & 63;
  const int wc   = t >> 6;          // 0..1 -> cols wc*80
  const int rb0  = blockIdx.x * 32;

  const int srow = t >> 2;          // staging: row 0..31
  const int skc  = (t & 3) * 8;     // k chunk of 8
  const int arow = rb0 + srow;
  const float* aptr = A + (size_t)arow * F_IN;

  const int lrow = lane & 15;
  const int lkb  = (lane >> 4) * 8;

  f32x4 acc[2][5];
#pragma unroll
  for (int i = 0; i < 2; i++)
#pragma unroll
    for (int j = 0; j < 5; j++) acc[i][j] = (f32x4){0.f,0.f,0.f,0.f};

  auto loadA = [&](int s, float4& q0, float4& q1) {
    int k = s*32 + skc;
    if (arow < N_NODES && k + 8 <= F_IN) {
      q0 = *(const float4*)(aptr + k);
      q1 = *(const float4*)(aptr + k + 4);
    } else {
      q0 = make_float4(0,0,0,0); q1 = q0;
    }
  };
  auto cvtStore = [&](int buf, const float4& q0, const float4& q1) {
    bf16x8 h;
    h[0]=(__bf16)q0.x; h[1]=(__bf16)q0.y; h[2]=(__bf16)q0.z; h[3]=(__bf16)q0.w;
    h[4]=(__bf16)q1.x; h[5]=(__bf16)q1.y; h[6]=(__bf16)q1.z; h[7]=(__bf16)q1.w;
    *(bf16x8*)&as[buf][srow*LSTR + skc] = h;
  };

  float4 pa0, pa1, pb0, pb1;
  loadA(0,  pa0, pa1);
  loadA(1,  pb0, pb1);
  cvtStore(0, pa0, pa1);
  __syncthreads();

  for (int s = 0; s < 63; s++) {
    const int cur = s & 1;
    bf16x8 af[2];
#pragma unroll
    for (int rf = 0; rf < 2; rf++)
      af[rf] = *(bf16x8*)&as[cur][(rf*16 + lrow)*LSTR + lkb];
    bf16x8 bfr[5];
#pragma unroll
    for (int cf = 0; cf < 5; cf++)
      bfr[cf] = *(const bf16x8*)(Bt + (size_t)(wc*80 + cf*16 + lrow)*KPAD + s*32 + lkb);

    if (s + 1 < 63) cvtStore(cur ^ 1, pb0, pb1);    // stage step s+1
    if (s + 2 < 63) loadA((s + 2), pa0, pa1);       // prefetch s+2

#pragma unroll
    for (int rf = 0; rf < 2; rf++)
#pragma unroll
      for (int cf = 0; cf < 5; cf++)
        acc[rf][cf] = __builtin_amdgcn_mfma_f32_16x16x32_bf16(af[rf], bfr[cf], acc[rf][cf], 0, 0, 0);
    __syncthreads();

    float4 t0 = pa0, t1 = pa1;     // rotate: pb <- s+2 data
    pa0 = pb0; pa1 = pb1;
    pb0 = t0;  pb1 = t1;
  }

  // epilogue: C/D layout col=lane&15, row=(lane>>4)*4 + j ; route to QS/KV
#pragma unroll
  for (int rf = 0; rf < 2; rf++) {
#pragma unroll
    for (int cf = 0; cf < 5; cf++) {
      int col = wc*80 + cf*16 + lrow;
      int et = col / 80, r = col % 80, mat = r / 20, d = r % 20;
      float bv = bias[col];
      __bf16* kvp = et ? KV1 : KV0;
#pragma unroll
      for (int j = 0; j < 4; j++) {
        int row = rb0 + rf*16 + (lane >> 4)*4 + j;
        if (row < N_NODES) {
          __bf16 val = (__bf16)(acc[rf][cf][j] + bv);
          if (mat < 2) QS[(size_t)row*80 + et*40 + mat*20 + d] = val;
          else         kvp[(size_t)row*64 + (mat-2)*20 + d]   = val;
        }
      }
    }
  }
}

// ---------------- layers 1..3 projection with inline BN+leakyReLU -----------------------
__launch_bounds__(256)
__global__ void proj_small_kernel(const float* __restrict__ xp, const float* __restrict__ bnl,
                                  const float* __restrict__ gam, const float* __restrict__ bet,
                                  const float* __restrict__ W, const float* __restrict__ bias,
                                  __bf16* __restrict__ QS,
                                  __bf16* __restrict__ KV0, __bf16* __restrict__ KV1)
{
  __shared__ float ws[20*160];
  __shared__ float xs[16*20];
  __shared__ float Ac[20], Bc[20];
  const int t = threadIdx.x;
  const int n0 = blockIdx.x * 16;
#pragma unroll
  for (int i = 0; i < 13; i++) {
    int idx = t + i*256;
    if (idx < 3200) ws[idx] = W[idx];
  }
  if (t < 20) {
    float s1 = 0.f, s2 = 0.f;
    for (int s = 0; s < NBNP; s++) { s1 += bnl[s*40 + t]; s2 += bnl[s*40 + 20 + t]; }
    float mu  = s1 * (1.f/N_NODES);
    float var = s2 * (1.f/N_NODES) - mu*mu;
    float a = rsqrtf(var + 1e-5f) * gam[t];
    Ac[t] = a; Bc[t] = bet[t] - mu*a;
  }
  __syncthreads();
#pragma unroll
  for (int i = 0; i < 2; i++) {
    int idx = t + i*256;
    if (idx < 320) {
      int nl = idx / 20, k = idx % 20;
      int n = n0 + nl;
      float x = (n < N_NODES) ? xp[(size_t)n*D + k] : 0.f;
      float y = x*Ac[k] + Bc[k];
      xs[idx] = (y > 0.f) ? y : 0.01f*y;
    }
  }
  __syncthreads();
#pragma unroll
  for (int i = 0; i < 10; i++) {
    int idx = t + i*256;
    int nl = idx / NCOL, col = idx % NCOL;
    int n = n0 + nl;
    if (n < N_NODES) {
      float acc = bias[col];
#pragma unroll
      for (int k = 0; k < 20; k++) acc += xs[nl*20 + k] * ws[k*NCOL + col];
      int et = col / 80, r = col % 80, mat = r / 20, d = r % 20;
      __bf16 val = (__bf16)acc;
      if (mat < 2) QS[(size_t)n*80 + et*40 + mat*20 + d] = val;
      else         (et ? KV1 : KV0)[(size_t)n*64 + (mat-2)*20 + d] = val;
    }
  }
}

// ---------------- fused attention + combine + BN partial sums ---------------------------
// 16 lanes per (node,et): wave = 2 nodes x 2 ets. Per-lane independent gathers (paired,
// 10 loads in flight). Reduction = 4 butterfly rounds over 16 lanes, serving 2 nodes/wave.
__launch_bounds__(256)
__global__ void attn_fused(const int* __restrict__ rp0, const int* __restrict__ adj0,
                           const int* __restrict__ rp1, const int* __restrict__ adj1,
                           const __bf16* __restrict__ QS,
                           const __bf16* __restrict__ KV0, const __bf16* __restrict__ KV1,
                           const float* __restrict__ w1, const float* __restrict__ w2, int l,
                           float* __restrict__ xpre, float* __restrict__ bnp)
{
  const int t    = threadIdx.x;
  const int wv   = t >> 6;
  const int lane = t & 63;
  const int g    = lane >> 4;         // group 0..3: (nodeA,et0)(nodeA,et1)(nodeB,et0)(nodeB,et1)
  const int sl   = lane & 15;
  const int et   = g & 1;
  const int node = blockIdx.x*8 + wv*2 + (g >> 1);   // grid = 6250 exactly

  const int* rowptr = et ? rp1 : rp0;
  const int* adj    = et ? adj1 : adj0;
  const __bf16* kvb = et ? KV1 : KV0;
  const __bf16* rq  = QS + (size_t)node*80 + et*40;   // q[0..20) s[20..40)

  float qf[20];
  {
    bf16x8 q0 = *(const bf16x8*)(rq);
    bf16x8 q1 = *(const bf16x8*)(rq + 8);
    bf16x4 q2 = *(const bf16x4*)(rq + 16);
#pragma unroll
    for (int i = 0; i < 8; i++) { qf[i] = (float)q0[i]; qf[8+i] = (float)q1[i]; }
#pragma unroll
    for (int i = 0; i < 4; i++) qf[16+i] = (float)q2[i];
  }

  const int beg = rowptr[node], end = rowptr[node+1];
  float z = 0.f;
  float S[20];
#pragma unroll
  for (int d = 0; d < 20; d++) S[d] = 0.f;

  int i = beg + sl;
  // paired loop: 2 edges (10 loads) in flight per lane
  for (; i + 16 < end; i += 32) {
    const int s0 = adj[i], s1 = adj[i+16];
    const __bf16* kva = kvb + (size_t)s0*64;
    const __bf16* kvc = kvb + (size_t)s1*64;
    bf16x8 a0 = *(const bf16x8*)(kva);
    bf16x8 a1 = *(const bf16x8*)(kva + 8);
    bf16x8 a2 = *(const bf16x8*)(kva + 16);
    bf16x8 a3 = *(const bf16x8*)(kva + 24);
    bf16x8 a4 = *(const bf16x8*)(kva + 32);
    bf16x8 b0 = *(const bf16x8*)(kvc);
    bf16x8 b1 = *(const bf16x8*)(kvc + 8);
    bf16x8 b2 = *(const bf16x8*)(kvc + 16);
    bf16x8 b3 = *(const bf16x8*)(kvc + 24);
    bf16x8 b4 = *(const bf16x8*)(kvc + 32);

    float d0 = 0.f, d1 = 0.f;
#pragma unroll
    for (int j = 0; j < 8; j++) { d0 += qf[j]*(float)a0[j];     d1 += qf[j]*(float)b0[j]; }
#pragma unroll
    for (int j = 0; j < 8; j++) { d0 += qf[8+j]*(float)a1[j];   d1 += qf[8+j]*(float)b1[j]; }
#pragma unroll
    for (int j = 0; j < 4; j++) { d0 += qf[16+j]*(float)a2[j];  d1 += qf[16+j]*(float)b2[j]; }
    const float w0 = __expf(fminf(d0*INV_SQRT_D, 80.f));
    const float w1v= __expf(fminf(d1*INV_SQRT_D, 80.f));
    z += w0 + w1v;
#pragma unroll
    for (int d = 0; d < 4; d++) S[d]     += w0*(float)a2[4+d] + w1v*(float)b2[4+d];
#pragma unroll
    for (int d = 0; d < 8; d++) S[4+d]   += w0*(float)a3[d]   + w1v*(float)b3[d];
#pragma unroll
    for (int d = 0; d < 8; d++) S[12+d]  += w0*(float)a4[d]   + w1v*(float)b4[d];
  }
  // tail: at most one edge per lane
  if (i < end) {
    const int s0 = adj[i];
    const __bf16* kva = kvb + (size_t)s0*64;
    bf16x8 a0 = *(const bf16x8*)(kva);
    bf16x8 a1 = *(const bf16x8*)(kva + 8);
    bf16x8 a2 = *(const bf16x8*)(kva + 16);
    bf16x8 a3 = *(const bf16x8*)(kva + 24);
    bf16x8 a4 = *(const bf16x8*)(kva + 32);
    float d0 = 0.f;
#pragma unroll
    for (int j = 0; j < 8; j++) d0 += qf[j]     * (float)a0[j];
#pragma unroll
    for (int j = 0; j < 8; j++) d0 += qf[8 + j] * (float)a1[j];
#pragma unroll
    for (int j = 0; j < 4; j++) d0 += qf[16 + j]* (float)a2[j];
    const float w0 = __expf(fminf(d0*INV_SQRT_D, 80.f));
    z += w0;
#pragma unroll
    for (int d = 0; d < 4; d++) S[d]     += w0*(float)a2[4+d];
#pragma unroll
    for (int d = 0; d < 8; d++) S[4+d]   += w0*(float)a3[d];
#pragma unroll
    for (int d = 0; d < 8; d++) S[12+d]  += w0*(float)a4[d];
  }

  // butterfly sum within each 16-lane group (4 rounds)
#pragma unroll
  for (int o = 8; o >= 1; o >>= 1) {
    z += __shfl_xor(z, o, 64);
#pragma unroll
    for (int d = 0; d < 20; d++) S[d] += __shfl_xor(S[d], o, 64);
  }

  // per-(node,et) output: S/z + skip (s at rq+20)
  const float inv = (z > 0.f) ? 1.f/z : 0.f;
  float outv[20];
  {
    bf16x4 s0 = *(const bf16x4*)(rq + 20);
    bf16x8 s1 = *(const bf16x8*)(rq + 24);
    bf16x8 s2 = *(const bf16x8*)(rq + 32);
#pragma unroll
    for (int i2 = 0; i2 < 4; i2++) outv[i2] = S[i2]*inv + (float)s0[i2];
#pragma unroll
    for (int i2 = 0; i2 < 8; i2++) { outv[4+i2]  = S[4+i2]*inv  + (float)s1[i2];
                                     outv[12+i2] = S[12+i2]*inv + (float)s2[i2]; }
  }

  // cross-et combine: lane ^ 16 flips et within the same node
  const float wa = w1[l], wb = w2[l];
  const float c0 = wa/(wa+wb), c1 = wb/(wa+wb);
  const float cme = et ? c1 : c0;
  const float cot = et ? c0 : c1;
  float x[20];
#pragma unroll
  for (int d = 0; d < 20; d++) {
    float o2 = __shfl_xor(outv[d], 16, 64);
    x[d] = cme*outv[d] + cot*o2;
  }

  if (et == 0 && sl == 0) {     // lanes 0 and 32 write their node's row
    float* xo = xpre + (size_t)node*D;
#pragma unroll
    for (int j = 0; j < 5; j++) {
      float4 o4 = make_float4(x[4*j], x[4*j+1], x[4*j+2], x[4*j+3]);
      *(float4*)(xo + 4*j) = o4;
    }
  }

  // BN partials: lane sl covers d=sl; lanes 0-3 also cover d=16+sl (16 lanes < 20 dims)
  float v = x[0];
#pragma unroll
  for (int d = 1; d < 16; d++) v = (sl == d) ? x[d] : v;
  float v2 = x[16];
#pragma unroll
  for (int d = 1; d < 4; d++) v2 = (sl == d) ? x[16 + d] : v2;

  float* slot = bnp + (size_t)(node & (NBNP-1))*40;
  if (et == 0) {
    atomicAdd(&slot[sl], v);
    if (sl < 4) atomicAdd(&slot[16 + sl], v2);
  } else {
    atomicAdd(&slot[20 + sl], v*v);
    if (sl < 4) atomicAdd(&slot[36 + sl], v2*v2);
  }
}

// ---------------- final: BN+lrelu (inline) on 4 layers, concat @ Wout + bout ------------
__launch_bounds__(256)
__global__ void final_kernel(const float* __restrict__ xpre4, const float* __restrict__ bnp,
                             const float* __restrict__ gam, const float* __restrict__ bet,
                             const float* __restrict__ Wout, const float* __restrict__ bout,
                             float* __restrict__ out)
{
  __shared__ float Ac[80], Bc[80], wlds[160];
  const int t = threadIdx.x;
  if (t < 80) {
    int l = t / 20, d = t % 20;
    const float* b = bnp + l*(NBNP*40);
    float s1 = 0.f, s2 = 0.f;
    for (int s = 0; s < NBNP; s++) { s1 += b[s*40 + d]; s2 += b[s*40 + 20 + d]; }
    float mu  = s1 * (1.f/N_NODES);
    float var = s2 * (1.f/N_NODES) - mu*mu;
    float a = rsqrtf(var + 1e-5f) * gam[t];
    Ac[t] = a; Bc[t] = bet[t] - mu*a;
  }
  if (t < 160) wlds[t] = Wout[t];
  __syncthreads();

  const int n = blockIdx.x*256 + t;
  if (n >= N_NODES) return;
  float a0 = bout[0], a1 = bout[1];
#pragma unroll
  for (int l = 0; l < 4; l++) {
    const float* base = xpre4 + (size_t)l*N_NODES*D + (size_t)n*D;
#pragma unroll
    for (int d = 0; d < D; d++) {
      int idx = l*20 + d;
      float y = base[d]*Ac[idx] + Bc[idx];
      y = (y > 0.f) ? y : 0.01f*y;
      a0 += y * wlds[idx*2 + 0];
      a1 += y * wlds[idx*2 + 1];
    }
  }
  out[n*2+0] = a0;
  out[n*2+1] = a1;
}

// ----------------------------------------------------------------------------------------
extern "C" void kernel_launch(void* const* d_in, const int* in_sizes, int n_in,
                              void* d_out, int out_size, void* d_ws, size_t ws_size,
                              hipStream_t stream)
{
  const float* feat = (const float*)d_in[0];
  const int*   same = (const int*)d_in[1];
  const int*   diff = (const int*)d_in[2];
  const float* W0q = (const float*)d_in[3];
  const float* b0q = (const float*)d_in[4];
  const float* W0k = (const float*)d_in[5];
  const float* b0k = (const float*)d_in[6];
  const float* W0v = (const float*)d_in[7];
  const float* b0v = (const float*)d_in[8];
  const float* W0s = (const float*)d_in[9];
  const float* b0s = (const float*)d_in[10];
  const float* Wq  = (const float*)d_in[11];
  const float* bq  = (const float*)d_in[12];
  const float* Wk  = (const float*)d_in[13];
  const float* bk  = (const float*)d_in[14];
  const float* Wv  = (const float*)d_in[15];
  const float* bv  = (const float*)d_in[16];
  const float* Ws_ = (const float*)d_in[17];
  const float* bs_ = (const float*)d_in[18];
  const float* w1  = (const float*)d_in[19];
  const float* w2  = (const float*)d_in[20];
  const float* gamma = (const float*)d_in[21];
  const float* beta  = (const float*)d_in[22];
  const float* Wout  = (const float*)d_in[23];
  const float* bout  = (const float*)d_in[24];

  float* wsf  = (float*)d_ws;
  __bf16*  QS    = (__bf16*)wsf;                 // 4,000,000 bf16 [N][80]
  __bf16*  KV0   = (__bf16*)(wsf + 2000000);     // 3,200,000 bf16 rows of 64 (128B aligned)
  __bf16*  KV1   = (__bf16*)(wsf + 3600000);
  float*   XPRE4 = wsf + 5200000;                // 4,000,000  [4][N][20] pre-BN
  __bf16*  B0bf  = (__bf16*)(wsf + 9200000);     //   322,560 bf16
  float*   BIAS0 = wsf + 9361280;                //       160
  float*   WL    = wsf + 9361440;                //     9,600
  float*   BIASL = wsf + 9371040;                //       480
  float*   BNP   = wsf + 9371520;                //    10,240  [4][64][40]
  int*     ib    = (int*)(wsf + 9381760);
  int* DEG  = ib;                                // 100,000
  int* RP0  = ib + 100000;                       //  50,004
  int* RP1  = ib + 150004;                       //  50,004
  int* NX0  = ib + 200008;                       //  50,000
  int* NX1  = ib + 250008;                       //  50,000
  int* ADJ0 = ib + 300008;                       // 1,600,000
  int* ADJ1 = ib + 1900008;                      // 1,600,000

  // pack weights + zero BN partials/degrees
  const int packN = NCOL*KPAD + 160 + 9600 + 480 + 4*NBNP*40 + 2*N_NODES;  // 443,040
  pack_kernel<<<(packN + 255)/256, 256, 0, stream>>>(
      W0q, W0k, W0v, W0s, b0q, b0k, b0v, b0s,
      Wq, Wk, Wv, Ws_, bq, bk, bv, bs_,
      B0bf, BIAS0, WL, BIASL, BNP, DEG);

  // CSR by dst, per edge type (indices identical across layers)
  const long nchunk = (2L*E_EDGES + SC_CHUNK - 1) / SC_CHUNK;
  hist_kernel<<<(int)(nchunk*8), 256, 0, stream>>>(same, diff, DEG);
  scan_kernel<<<2, 1024, 0, stream>>>(DEG, RP0, RP1, NX0, NX1);
  scatter_kernel<<<(int)(nchunk*8), 256, 0, stream>>>(same, diff, NX0, NX1, ADJ0, ADJ1);

  for (int l = 0; l < 4; l++) {
    if (l == 0)
      gemm0_mfma<<<(N_NODES + 31)/32, 128, 0, stream>>>(feat, B0bf, BIAS0, QS, KV0, KV1);
    else
      proj_small_kernel<<<(N_NODES + 15)/16, 256, 0, stream>>>(
          XPRE4 + (size_t)(l-1)*N_NODES*D, BNP + (l-1)*(NBNP*40),
          gamma + (l-1)*D, beta + (l-1)*D,
          WL + (size_t)(l-1)*3200, BIASL + (size_t)(l-1)*160, QS, KV0, KV1);

    attn_fused<<<N_NODES/8, 256, 0, stream>>>(
        RP0, ADJ0, RP1, ADJ1, QS, KV0, KV1, w1, w2, l,
        XPRE4 + (size_t)l*N_NODES*D, BNP + l*(NBNP*40));
  }

  final_kernel<<<(N_NODES + 255)/256, 256, 0, stream>>>(
      XPRE4, BNP, gamma, beta, Wout, bout, (float*)d_out);
}

// Round 18
// 1018.905 us; speedup vs baseline: 1.0752x; 1.0752x over previous
//
#include <hip/hip_runtime.h>
#include <math.h>

#define N_NODES 50000
#define E_EDGES 1600000
#define F_IN    2000
#define D       20
#define NCOL    160   // 2 edge types * [q s k v] * 20
#define KPAD2   2048  // 2 * 1024
#define KHALF   1024
#define KSTEPS  32    // per half, 32 k each
#define NBNP    64    // BN partial slots
#define LSTR    40    // LDS row stride in bf16 (80B)

#define INV_SQRT_D 0.22360679774997896f

typedef __bf16 bf16x8 __attribute__((ext_vector_type(8)));
typedef __bf16 bf16x4 __attribute__((ext_vector_type(4)));
typedef float  f32x4  __attribute__((ext_vector_type(4)));

// Layouts:
//   QS[node][et*40 + mat*20 + d]  (mat 0=q,1=s), 160B rows
//   KV[et][node*64 + mat2*20 + d] (mat2 0=k,1=v), 128B-aligned rows
//   CP[kh][node*160 + col] fp32 partial products of layer-0 GEMM (K-split halves)

// ---------------- pack weights + zero accumulators --------------------------------------
__global__ void pack_kernel(
    const float* __restrict__ W0q, const float* __restrict__ W0k,
    const float* __restrict__ W0v, const float* __restrict__ W0s,
    const float* __restrict__ b0q, const float* __restrict__ b0k,
    const float* __restrict__ b0v, const float* __restrict__ b0s,
    const float* __restrict__ Wq,  const float* __restrict__ Wk,
    const float* __restrict__ Wv,  const float* __restrict__ Ws_,
    const float* __restrict__ bq,  const float* __restrict__ bk,
    const float* __restrict__ bv,  const float* __restrict__ bs_,
    __bf16* __restrict__ B0, float* __restrict__ bias0,
    float* __restrict__ WL, float* __restrict__ biasL,
    float* __restrict__ bnp, int* __restrict__ deg)
{
  long idx = (long)blockIdx.x * blockDim.x + threadIdx.x;
  if (idx < (long)NCOL*KPAD2) {             // B0T: [160][2048] bf16
    int col = (int)(idx / KPAD2), k = (int)(idx % KPAD2);
    int et = col / 80, r = col % 80, mat = r / 20, d = r % 20;
    const float* w = (mat==0)?W0q:(mat==1)?W0s:(mat==2)?W0k:W0v;
    float v = (k < F_IN) ? w[((size_t)et*F_IN + k)*D + d] : 0.f;
    B0[idx] = (__bf16)v;
    return;
  }
  idx -= (long)NCOL*KPAD2;
  if (idx < 160) {                          // bias0
    int col = (int)idx;
    int et = col / 80, r = col % 80, mat = r / 20, d = r % 20;
    const float* b = (mat==0)?b0q:(mat==1)?b0s:(mat==2)?b0k:b0v;
    bias0[col] = b[et*D + d];
    return;
  }
  idx -= 160;
  if (idx < 9600) {                         // WL: 3 x [20][160]
    int l = (int)(idx / 3200), rem = (int)(idx % 3200);
    int k = rem / NCOL, col = rem % NCOL;
    int et = col / 80, r = col % 80, mat = r / 20, d = r % 20;
    const float* w = (mat==0)?Wq:(mat==1)?Ws_:(mat==2)?Wk:Wv;
    WL[idx] = w[(((size_t)l*2 + et)*D + k)*D + d];
    return;
  }
  idx -= 9600;
  if (idx < 480) {                          // biasL: 3 x [160]
    int l = (int)(idx / NCOL), col = (int)(idx % NCOL);
    int et = col / 80, r = col % 80, mat = r / 20, d = r % 20;
    const float* b = (mat==0)?bq:(mat==1)?bs_:(mat==2)?bk:bv;
    biasL[idx] = b[(l*2 + et)*D + d];
    return;
  }
  idx -= 480;
  if (idx < 4*NBNP*40) { bnp[idx] = 0.f; return; } // BN partials: [4][64][40]
  idx -= 4*NBNP*40;
  if (idx < 2*N_NODES) { deg[idx] = 0; return; }
}

// ---------------- CSR helpers (XCD-partitioned) ------------------------------------------
#define SC_EPT 16
#define SC_CHUNK (256*SC_EPT)

__global__ void scan_kernel(const int* __restrict__ deg,
                            int* __restrict__ rowptr0, int* __restrict__ rowptr1,
                            int* __restrict__ next0, int* __restrict__ next1)
{
  const int et = blockIdx.x;
  const int* dg = deg + (size_t)et*N_NODES;
  int* rp = et ? rowptr1 : rowptr0;
  int* np = et ? next1 : next0;
  __shared__ int part[1024];
  const int t = threadIdx.x;
  const int per = (N_NODES + 1023) / 1024;  // 49
  const int b = t * per;
  const int e = (b + per < N_NODES) ? (b + per) : N_NODES;
  int s = 0;
  for (int i = b; i < e; i++) s += dg[i];
  part[t] = s;
  __syncthreads();
  for (int o = 1; o < 1024; o <<= 1) {
    int v = (t >= o) ? part[t-o] : 0;
    __syncthreads();
    part[t] += v;
    __syncthreads();
  }
  int run = (t == 0) ? 0 : part[t-1];
  for (int i = b; i < e; i++) {
    rp[i] = run; np[i] = run;
    run += dg[i];
  }
  if (t == 0) rp[N_NODES] = part[1023];
}

// ---------------- K1: gemm0 K-split partials (blocks 0..GB) + hist (rest) ---------------
// gemm0: 64-row tile x half-K (1024). 1564 blocks x 4 waves = 6256 waves (2x occupancy).
// Partial C written fp32 to CP[kh]; bias added in combine.
__launch_bounds__(256)
__global__ void k1_gemm0_hist(const float* __restrict__ A,
                              const __bf16* __restrict__ Bt,
                              float* __restrict__ CP,
                              const int* __restrict__ same, const int* __restrict__ diff,
                              int* __restrict__ deg, int gemmBlocks)
{
  if ((int)blockIdx.x >= gemmBlocks) {
    // ---- hist ----
    const int bid   = blockIdx.x - gemmBlocks;
    const int part  = bid & 7;
    const int chunk = bid >> 3;
    const int lo = part * (N_NODES/8);
    const int hi = lo + (N_NODES/8);
    const long i0 = (long)chunk * SC_CHUNK + threadIdx.x;
#pragma unroll
    for (int it = 0; it < SC_EPT; ++it) {
      long i = i0 + (long)it*256;
      if (i >= 2L*E_EDGES) break;
      int et = (i >= E_EDGES) ? 1 : 0;
      long e = i - (long)et*E_EDGES;
      const int* ix = et ? diff : same;
      int dst = ix[E_EDGES + e];
      if (dst >= lo && dst < hi)
        atomicAdd(&deg[(size_t)et*N_NODES + dst], 1);
    }
    return;
  }

  // ---- gemm0 partial ----
  __shared__ __bf16 as[2][64*LSTR];
  const int tile = blockIdx.x >> 1;
  const int kh   = blockIdx.x & 1;
  const int t    = threadIdx.x;
  const int lane = t & 63;
  const int wid  = t >> 6;          // 0..3
  const int wr   = wid >> 1;        // 0..1 -> rows wr*32
  const int wc   = wid & 1;         // 0..1 -> cols wc*80
  const int rb0  = tile * 64;

  const int srow = t >> 2;          // staging: row 0..63
  const int skc  = (t & 3) * 8;     // k chunk of 8
  const int arow = rb0 + srow;
  const float* aptr = A + (size_t)arow * F_IN;

  const int lrow = lane & 15;
  const int lkb  = (lane >> 4) * 8;

  f32x4 acc[2][5];
#pragma unroll
  for (int i = 0; i < 2; i++)
#pragma unroll
    for (int j = 0; j < 5; j++) acc[i][j] = (f32x4){0.f,0.f,0.f,0.f};

  auto loadA = [&](int s, float4& q0, float4& q1) {
    int k = kh*KHALF + s*32 + skc;
    if (arow < N_NODES && k + 8 <= F_IN) {
      q0 = *(const float4*)(aptr + k);
      q1 = *(const float4*)(aptr + k + 4);
    } else {
      q0 = make_float4(0,0,0,0); q1 = q0;
    }
  };
  auto cvtStore = [&](int buf, const float4& q0, const float4& q1) {
    bf16x8 h;
    h[0]=(__bf16)q0.x; h[1]=(__bf16)q0.y; h[2]=(__bf16)q0.z; h[3]=(__bf16)q0.w;
    h[4]=(__bf16)q1.x; h[5]=(__bf16)q1.y; h[6]=(__bf16)q1.z; h[7]=(__bf16)q1.w;
    *(bf16x8*)&as[buf][srow*LSTR + skc] = h;
  };

  float4 pa0, pa1, pb0, pb1;
  loadA(0, pa0, pa1);
  loadA(1, pb0, pb1);
  cvtStore(0, pa0, pa1);
  __syncthreads();

  for (int s = 0; s < KSTEPS; s++) {
    const int cur = s & 1;
    bf16x8 af[2];
#pragma unroll
    for (int rf = 0; rf < 2; rf++)
      af[rf] = *(bf16x8*)&as[cur][(wr*32 + rf*16 + lrow)*LSTR + lkb];
    bf16x8 bfr[5];
#pragma unroll
    for (int cf = 0; cf < 5; cf++)
      bfr[cf] = *(const bf16x8*)(Bt + (size_t)(wc*80 + cf*16 + lrow)*KPAD2 + kh*KHALF + s*32 + lkb);

    if (s + 1 < KSTEPS) cvtStore(cur ^ 1, pb0, pb1);
    if (s + 2 < KSTEPS) loadA(s + 2, pa0, pa1);

#pragma unroll
    for (int rf = 0; rf < 2; rf++)
#pragma unroll
      for (int cf = 0; cf < 5; cf++)
        acc[rf][cf] = __builtin_amdgcn_mfma_f32_16x16x32_bf16(af[rf], bfr[cf], acc[rf][cf], 0, 0, 0);
    __syncthreads();

    float4 t0 = pa0, t1 = pa1;
    pa0 = pb0; pa1 = pb1;
    pb0 = t0;  pb1 = t1;
  }

  // epilogue: fp32 partials to CP[kh]
  float* cp = CP + (size_t)kh*N_NODES*NCOL;
#pragma unroll
  for (int rf = 0; rf < 2; rf++) {
#pragma unroll
    for (int cf = 0; cf < 5; cf++) {
      int col = wc*80 + cf*16 + lrow;
#pragma unroll
      for (int j = 0; j < 4; j++) {
        int row = rb0 + wr*32 + rf*16 + (lane >> 4)*4 + j;
        if (row < N_NODES) cp[(size_t)row*NCOL + col] = acc[rf][cf][j];
      }
    }
  }
}

// ---------------- K2: combine CP halves -> QS/KV (blocks 0..CB) + scatter (rest) --------
__launch_bounds__(256)
__global__ void k2_combine_scatter(const float* __restrict__ CP, const float* __restrict__ bias,
                                   __bf16* __restrict__ QS,
                                   __bf16* __restrict__ KV0, __bf16* __restrict__ KV1,
                                   const int* __restrict__ same, const int* __restrict__ diff,
                                   int* __restrict__ next0, int* __restrict__ next1,
                                   int* __restrict__ adj0, int* __restrict__ adj1,
                                   int combBlocks)
{
  if ((int)blockIdx.x >= combBlocks) {
    // ---- scatter ----
    const int bid   = blockIdx.x - combBlocks;
    const int part  = bid & 7;
    const int chunk = bid >> 3;
    const int lo = part * (N_NODES/8);
    const int hi = lo + (N_NODES/8);
    const long i0 = (long)chunk * SC_CHUNK + threadIdx.x;
#pragma unroll
    for (int it = 0; it < SC_EPT; ++it) {
      long i = i0 + (long)it*256;
      if (i >= 2L*E_EDGES) break;
      int et = (i >= E_EDGES) ? 1 : 0;
      long e = i - (long)et*E_EDGES;
      const int* ix = et ? diff : same;
      int dst = ix[E_EDGES + e];
      if (dst >= lo && dst < hi) {
        int src = ix[e];
        int* np  = et ? next1 : next0;
        int* adj = et ? adj1  : adj0;
        int pos = atomicAdd(&np[dst], 1);
        adj[pos] = src;
      }
    }
    return;
  }

  // ---- combine: 4 elems per thread; 4-col groups never cross a 20-col mat boundary ----
  const long base = ((long)blockIdx.x*256 + threadIdx.x) * 4;
  if (base >= (long)N_NODES*NCOL) return;
  const int row = (int)(base / NCOL);
  const int col = (int)(base % NCOL);
  float4 a = *(const float4*)(CP + base);
  float4 b = *(const float4*)(CP + (size_t)N_NODES*NCOL + base);
  float4 bi = *(const float4*)(bias + col);
  float v[4] = { a.x+b.x+bi.x, a.y+b.y+bi.y, a.z+b.z+bi.z, a.w+b.w+bi.w };

  const int et = col / 80, r = col % 80, mat = r / 20, d = r % 20;
  if (mat < 2) {
    __bf16* q = QS + (size_t)row*80 + et*40 + mat*20 + d;
#pragma unroll
    for (int j = 0; j < 4; j++) q[j] = (__bf16)v[j];
  } else {
    __bf16* kv = (et ? KV1 : KV0) + (size_t)row*64 + (mat-2)*20 + d;
#pragma unroll
    for (int j = 0; j < 4; j++) kv[j] = (__bf16)v[j];
  }
}

// ---------------- layers 1..3 projection with inline BN+leakyReLU -----------------------
__launch_bounds__(256)
__global__ void proj_small_kernel(const float* __restrict__ xp, const float* __restrict__ bnl,
                                  const float* __restrict__ gam, const float* __restrict__ bet,
                                  const float* __restrict__ W, const float* __restrict__ bias,
                                  __bf16* __restrict__ QS,
                                  __bf16* __restrict__ KV0, __bf16* __restrict__ KV1)
{
  __shared__ float ws[20*160];
  __shared__ float xs[16*20];
  __shared__ float Ac[20], Bc[20];
  const int t = threadIdx.x;
  const int n0 = blockIdx.x * 16;
#pragma unroll
  for (int i = 0; i < 13; i++) {
    int idx = t + i*256;
    if (idx < 3200) ws[idx] = W[idx];
  }
  if (t < 20) {
    float s1 = 0.f, s2 = 0.f;
    for (int s = 0; s < NBNP; s++) { s1 += bnl[s*40 + t]; s2 += bnl[s*40 + 20 + t]; }
    float mu  = s1 * (1.f/N_NODES);
    float var = s2 * (1.f/N_NODES) - mu*mu;
    float a = rsqrtf(var + 1e-5f) * gam[t];
    Ac[t] = a; Bc[t] = bet[t] - mu*a;
  }
  __syncthreads();
#pragma unroll
  for (int i = 0; i < 2; i++) {
    int idx = t + i*256;
    if (idx < 320) {
      int nl = idx / 20, k = idx % 20;
      int n = n0 + nl;
      float x = (n < N_NODES) ? xp[(size_t)n*D + k] : 0.f;
      float y = x*Ac[k] + Bc[k];
      xs[idx] = (y > 0.f) ? y : 0.01f*y;
    }
  }
  __syncthreads();
#pragma unroll
  for (int i = 0; i < 10; i++) {
    int idx = t + i*256;
    int nl = idx / NCOL, col = idx % NCOL;
    int n = n0 + nl;
    if (n < N_NODES) {
      float acc = bias[col];
#pragma unroll
      for (int k = 0; k < 20; k++) acc += xs[nl*20 + k] * ws[k*NCOL + col];
      int et = col / 80, r = col % 80, mat = r / 20, d = r % 20;
      __bf16 val = (__bf16)acc;
      if (mat < 2) QS[(size_t)n*80 + et*40 + mat*20 + d] = val;
      else         (et ? KV1 : KV0)[(size_t)n*64 + (mat-2)*20 + d] = val;
    }
  }
}

// ---------------- fused attention + combine + BN partial sums ---------------------------
// 16 lanes per (node,et): wave = 2 nodes x 2 ets.
__launch_bounds__(256)
__global__ void attn_fused(const int* __restrict__ rp0, const int* __restrict__ adj0,
                           const int* __restrict__ rp1, const int* __restrict__ adj1,
                           const __bf16* __restrict__ QS,
                           const __bf16* __restrict__ KV0, const __bf16* __restrict__ KV1,
                           const float* __restrict__ w1, const float* __restrict__ w2, int l,
                           float* __restrict__ xpre, float* __restrict__ bnp)
{
  const int t    = threadIdx.x;
  const int wv   = t >> 6;
  const int lane = t & 63;
  const int g    = lane >> 4;
  const int sl   = lane & 15;
  const int et   = g & 1;
  const int node = blockIdx.x*8 + wv*2 + (g >> 1);   // grid = 6250 exactly

  const int* rowptr = et ? rp1 : rp0;
  const int* adj    = et ? adj1 : adj0;
  const __bf16* kvb = et ? KV1 : KV0;
  const __bf16* rq  = QS + (size_t)node*80 + et*40;

  float qf[20];
  {
    bf16x8 q0 = *(const bf16x8*)(rq);
    bf16x8 q1 = *(const bf16x8*)(rq + 8);
    bf16x4 q2 = *(const bf16x4*)(rq + 16);
#pragma unroll
    for (int i = 0; i < 8; i++) { qf[i] = (float)q0[i]; qf[8+i] = (float)q1[i]; }
#pragma unroll
    for (int i = 0; i < 4; i++) qf[16+i] = (float)q2[i];
  }

  const int beg = rowptr[node], end = rowptr[node+1];
  float z = 0.f;
  float S[20];
#pragma unroll
  for (int d = 0; d < 20; d++) S[d] = 0.f;

  int i = beg + sl;
  for (; i + 16 < end; i += 32) {
    const int s0 = adj[i], s1 = adj[i+16];
    const __bf16* kva = kvb + (size_t)s0*64;
    const __bf16* kvc = kvb + (size_t)s1*64;
    bf16x8 a0 = *(const bf16x8*)(kva);
    bf16x8 a1 = *(const bf16x8*)(kva + 8);
    bf16x8 a2 = *(const bf16x8*)(kva + 16);
    bf16x8 a3 = *(const bf16x8*)(kva + 24);
    bf16x8 a4 = *(const bf16x8*)(kva + 32);
    bf16x8 b0 = *(const bf16x8*)(kvc);
    bf16x8 b1 = *(const bf16x8*)(kvc + 8);
    bf16x8 b2 = *(const bf16x8*)(kvc + 16);
    bf16x8 b3 = *(const bf16x8*)(kvc + 24);
    bf16x8 b4 = *(const bf16x8*)(kvc + 32);

    float d0 = 0.f, d1 = 0.f;
#pragma unroll
    for (int j = 0; j < 8; j++) { d0 += qf[j]*(float)a0[j];     d1 += qf[j]*(float)b0[j]; }
#pragma unroll
    for (int j = 0; j < 8; j++) { d0 += qf[8+j]*(float)a1[j];   d1 += qf[8+j]*(float)b1[j]; }
#pragma unroll
    for (int j = 0; j < 4; j++) { d0 += qf[16+j]*(float)a2[j];  d1 += qf[16+j]*(float)b2[j]; }
    const float w0 = __expf(fminf(d0*INV_SQRT_D, 80.f));
    const float w1v= __expf(fminf(d1*INV_SQRT_D, 80.f));
    z += w0 + w1v;
#pragma unroll
    for (int d = 0; d < 4; d++) S[d]     += w0*(float)a2[4+d] + w1v*(float)b2[4+d];
#pragma unroll
    for (int d = 0; d < 8; d++) S[4+d]   += w0*(float)a3[d]   + w1v*(float)b3[d];
#pragma unroll
    for (int d = 0; d < 8; d++) S[12+d]  += w0*(float)a4[d]   + w1v*(float)b4[d];
  }
  if (i < end) {
    const int s0 = adj[i];
    const __bf16* kva = kvb + (size_t)s0*64;
    bf16x8 a0 = *(const bf16x8*)(kva);
    bf16x8 a1 = *(const bf16x8*)(kva + 8);
    bf16x8 a2 = *(const bf16x8*)(kva + 16);
    bf16x8 a3 = *(const bf16x8*)(kva + 24);
    bf16x8 a4 = *(const bf16x8*)(kva + 32);
    float d0 = 0.f;
#pragma unroll
    for (int j = 0; j < 8; j++) d0 += qf[j]     * (float)a0[j];
#pragma unroll
    for (int j = 0; j < 8; j++) d0 += qf[8 + j] * (float)a1[j];
#pragma unroll
    for (int j = 0; j < 4; j++) d0 += qf[16 + j]* (float)a2[j];
    const float w0 = __expf(fminf(d0*INV_SQRT_D, 80.f));
    z += w0;
#pragma unroll
    for (int d = 0; d < 4; d++) S[d]     += w0*(float)a2[4+d];
#pragma unroll
    for (int d = 0; d < 8; d++) S[4+d]   += w0*(float)a3[d];
#pragma unroll
    for (int d = 0; d < 8; d++) S[12+d]  += w0*(float)a4[d];
  }

#pragma unroll
  for (int o = 8; o >= 1; o >>= 1) {
    z += __shfl_xor(z, o, 64);
#pragma unroll
    for (int d = 0; d < 20; d++) S[d] += __shfl_xor(S[d], o, 64);
  }

  const float inv = (z > 0.f) ? 1.f/z : 0.f;
  float outv[20];
  {
    bf16x4 s0 = *(const bf16x4*)(rq + 20);
    bf16x8 s1 = *(const bf16x8*)(rq + 24);
    bf16x8 s2 = *(const bf16x8*)(rq + 32);
#pragma unroll
    for (int i2 = 0; i2 < 4; i2++) outv[i2] = S[i2]*inv + (float)s0[i2];
#pragma unroll
    for (int i2 = 0; i2 < 8; i2++) { outv[4+i2]  = S[4+i2]*inv  + (float)s1[i2];
                                     outv[12+i2] = S[12+i2]*inv + (float)s2[i2]; }
  }

  const float wa = w1[l], wb = w2[l];
  const float c0 = wa/(wa+wb), c1 = wb/(wa+wb);
  const float cme = et ? c1 : c0;
  const float cot = et ? c0 : c1;
  float x[20];
#pragma unroll
  for (int d = 0; d < 20; d++) {
    float o2 = __shfl_xor(outv[d], 16, 64);
    x[d] = cme*outv[d] + cot*o2;
  }

  if (et == 0 && sl == 0) {
    float* xo = xpre + (size_t)node*D;
#pragma unroll
    for (int j = 0; j < 5; j++) {
      float4 o4 = make_float4(x[4*j], x[4*j+1], x[4*j+2], x[4*j+3]);
      *(float4*)(xo + 4*j) = o4;
    }
  }

  float v = x[0];
#pragma unroll
  for (int d = 1; d < 16; d++) v = (sl == d) ? x[d] : v;
  float v2 = x[16];
#pragma unroll
  for (int d = 1; d < 4; d++) v2 = (sl == d) ? x[16 + d] : v2;

  float* slot = bnp + (size_t)(node & (NBNP-1))*40;
  if (et == 0) {
    atomicAdd(&slot[sl], v);
    if (sl < 4) atomicAdd(&slot[16 + sl], v2);
  } else {
    atomicAdd(&slot[20 + sl], v*v);
    if (sl < 4) atomicAdd(&slot[36 + sl], v2*v2);
  }
}

// ---------------- final: BN+lrelu (inline) on 4 layers, concat @ Wout + bout ------------
__launch_bounds__(256)
__global__ void final_kernel(const float* __restrict__ xpre4, const float* __restrict__ bnp,
                             const float* __restrict__ gam, const float* __restrict__ bet,
                             const float* __restrict__ Wout, const float* __restrict__ bout,
                             float* __restrict__ out)
{
  __shared__ float Ac[80], Bc[80], wlds[160];
  const int t = threadIdx.x;
  if (t < 80) {
    int l = t / 20, d = t % 20;
    const float* b = bnp + l*(NBNP*40);
    float s1 = 0.f, s2 = 0.f;
    for (int s = 0; s < NBNP; s++) { s1 += b[s*40 + d]; s2 += b[s*40 + 20 + d]; }
    float mu  = s1 * (1.f/N_NODES);
    float var = s2 * (1.f/N_NODES) - mu*mu;
    float a = rsqrtf(var + 1e-5f) * gam[t];
    Ac[t] = a; Bc[t] = bet[t] - mu*a;
  }
  if (t < 160) wlds[t] = Wout[t];
  __syncthreads();

  const int n = blockIdx.x*256 + t;
  if (n >= N_NODES) return;
  float a0 = bout[0], a1 = bout[1];
#pragma unroll
  for (int l = 0; l < 4; l++) {
    const float* base = xpre4 + (size_t)l*N_NODES*D + (size_t)n*D;
#pragma unroll
    for (int d = 0; d < D; d++) {
      int idx = l*20 + d;
      float y = base[d]*Ac[idx] + Bc[idx];
      y = (y > 0.f) ? y : 0.01f*y;
      a0 += y * wlds[idx*2 + 0];
      a1 += y * wlds[idx*2 + 1];
    }
  }
  out[n*2+0] = a0;
  out[n*2+1] = a1;
}

// ----------------------------------------------------------------------------------------
extern "C" void kernel_launch(void* const* d_in, const int* in_sizes, int n_in,
                              void* d_out, int out_size, void* d_ws, size_t ws_size,
                              hipStream_t stream)
{
  const float* feat = (const float*)d_in[0];
  const int*   same = (const int*)d_in[1];
  const int*   diff = (const int*)d_in[2];
  const float* W0q = (const float*)d_in[3];
  const float* b0q = (const float*)d_in[4];
  const float* W0k = (const float*)d_in[5];
  const float* b0k = (const float*)d_in[6];
  const float* W0v = (const float*)d_in[7];
  const float* b0v = (const float*)d_in[8];
  const float* W0s = (const float*)d_in[9];
  const float* b0s = (const float*)d_in[10];
  const float* Wq  = (const float*)d_in[11];
  const float* bq  = (const float*)d_in[12];
  const float* Wk  = (const float*)d_in[13];
  const float* bk  = (const float*)d_in[14];
  const float* Wv  = (const float*)d_in[15];
  const float* bv  = (const float*)d_in[16];
  const float* Ws_ = (const float*)d_in[17];
  const float* bs_ = (const float*)d_in[18];
  const float* w1  = (const float*)d_in[19];
  const float* w2  = (const float*)d_in[20];
  const float* gamma = (const float*)d_in[21];
  const float* beta  = (const float*)d_in[22];
  const float* Wout  = (const float*)d_in[23];
  const float* bout  = (const float*)d_in[24];

  float* wsf  = (float*)d_ws;
  __bf16*  QS    = (__bf16*)wsf;                 // 4,000,000 bf16 [N][80]
  __bf16*  KV0   = (__bf16*)(wsf + 2000000);     // 3,200,000 bf16 rows of 64
  __bf16*  KV1   = (__bf16*)(wsf + 3600000);
  float*   XPRE4 = wsf + 5200000;                // 4,000,000  [4][N][20]
  __bf16*  B0bf  = (__bf16*)(wsf + 9200000);     //   327,680 bf16 = 163,840 f
  float*   BIAS0 = wsf + 9363840;                //       160
  float*   WL    = wsf + 9364000;                //     9,600
  float*   BIASL = wsf + 9373600;                //       480
  float*   BNP   = wsf + 9374080;                //    10,240  [4][64][40]
  float*   CP    = wsf + 9400000;                // 16,000,000 fp32 [2][N][160]
  int*     ib    = (int*)(wsf + 25400000);
  int* DEG  = ib;                                // 100,000
  int* RP0  = ib + 100000;                       //  50,004
  int* RP1  = ib + 150004;                       //  50,004
  int* NX0  = ib + 200008;                       //  50,000
  int* NX1  = ib + 250008;                       //  50,000
  int* ADJ0 = ib + 300008;                       // 1,600,000
  int* ADJ1 = ib + 1900008;                      // 1,600,000

  // pack weights + zero BN partials/degrees
  const int packN = NCOL*KPAD2 + 160 + 9600 + 480 + 4*NBNP*40 + 2*N_NODES;  // 448,160
  pack_kernel<<<(packN + 255)/256, 256, 0, stream>>>(
      W0q, W0k, W0v, W0s, b0q, b0k, b0v, b0s,
      Wq, Wk, Wv, Ws_, bq, bk, bv, bs_,
      B0bf, BIAS0, WL, BIASL, BNP, DEG);

  const long nchunk = (2L*E_EDGES + SC_CHUNK - 1) / SC_CHUNK;   // 782
  const int histBlocks = (int)(nchunk*8);                       // 6256
  const int gemmBlocks = ((N_NODES + 63)/64) * 2;               // 1564
  const int combBlocks = (int)(((long)N_NODES*NCOL/4 + 255) / 256);  // 7813

  // K1: gemm0 K-split partials (6256 waves) overlapped with hist
  k1_gemm0_hist<<<gemmBlocks + histBlocks, 256, 0, stream>>>(
      feat, B0bf, CP, same, diff, DEG, gemmBlocks);

  scan_kernel<<<2, 1024, 0, stream>>>(DEG, RP0, RP1, NX0, NX1);

  // K2: combine halves -> QS/KV overlapped with scatter
  k2_combine_scatter<<<combBlocks + histBlocks, 256, 0, stream>>>(
      CP, BIAS0, QS, KV0, KV1, same, diff, NX0, NX1, ADJ0, ADJ1, combBlocks);

  for (int l = 0; l < 4; l++) {
    if (l > 0)
      proj_small_kernel<<<(N_NODES + 15)/16, 256, 0, stream>>>(
          XPRE4 + (size_t)(l-1)*N_NODES*D, BNP + (l-1)*(NBNP*40),
          gamma + (l-1)*D, beta + (l-1)*D,
          WL + (size_t)(l-1)*3200, BIASL + (size_t)(l-1)*160, QS, KV0, KV1);

    attn_fused<<<N_NODES/8, 256, 0, stream>>>(
        RP0, ADJ0, RP1, ADJ1, QS, KV0, KV1, w1, w2, l,
        XPRE4 + (size_t)l*N_NODES*D, BNP + l*(NBNP*40));
  }

  final_kernel<<<(N_NODES + 255)/256, 256, 0, stream>>>(
      XPRE4, BNP, gamma, beta, Wout, bout, (float*)d_out);
}

// Round 19
// 972.005 us; speedup vs baseline: 1.1271x; 1.0483x over previous
//
#include <hip/hip_runtime.h>
#include <math.h>

#define N_NODES 50000
#define E_EDGES 1600000
#define F_IN    2000
#define D       20
#define NCOL    160   // 2 edge types * [q s k v] * 20
#define KPAD    2016  // 63 * 32
#define NBNP    64    // BN partial slots
#define LSTR    40    // LDS row stride in bf16 (80B: bank-conflict-free, 16B aligned)

#define INV_SQRT_D 0.22360679774997896f

typedef __bf16 bf16x8 __attribute__((ext_vector_type(8)));
typedef __bf16 bf16x4 __attribute__((ext_vector_type(4)));
typedef float  f32x4  __attribute__((ext_vector_type(4)));

// Layouts:
//   QS[node][et*40 + mat*20 + d]  (mat 0=q,1=s), 160B rows
//   KV[et][node*64 + mat2*20 + d] (mat2 0=k,1=v), 128B-aligned rows, k+v in first 80B

// ---------------- pack weights + zero accumulators --------------------------------------
__global__ void pack_kernel(
    const float* __restrict__ W0q, const float* __restrict__ W0k,
    const float* __restrict__ W0v, const float* __restrict__ W0s,
    const float* __restrict__ b0q, const float* __restrict__ b0k,
    const float* __restrict__ b0v, const float* __restrict__ b0s,
    const float* __restrict__ Wq,  const float* __restrict__ Wk,
    const float* __restrict__ Wv,  const float* __restrict__ Ws_,
    const float* __restrict__ bq,  const float* __restrict__ bk,
    const float* __restrict__ bv,  const float* __restrict__ bs_,
    __bf16* __restrict__ B0, float* __restrict__ bias0,
    float* __restrict__ WL, float* __restrict__ biasL,
    float* __restrict__ bnp, int* __restrict__ deg)
{
  long idx = (long)blockIdx.x * blockDim.x + threadIdx.x;
  if (idx < (long)NCOL*KPAD) {              // B0T: [160][2016] bf16
    int col = (int)(idx / KPAD), k = (int)(idx % KPAD);
    int et = col / 80, r = col % 80, mat = r / 20, d = r % 20;
    const float* w = (mat==0)?W0q:(mat==1)?W0s:(mat==2)?W0k:W0v;
    float v = (k < F_IN) ? w[((size_t)et*F_IN + k)*D + d] : 0.f;
    B0[idx] = (__bf16)v;
    return;
  }
  idx -= (long)NCOL*KPAD;
  if (idx < 160) {                          // bias0
    int col = (int)idx;
    int et = col / 80, r = col % 80, mat = r / 20, d = r % 20;
    const float* b = (mat==0)?b0q:(mat==1)?b0s:(mat==2)?b0k:b0v;
    bias0[col] = b[et*D + d];
    return;
  }
  idx -= 160;
  if (idx < 9600) {                         // WL: 3 x [20][160]
    int l = (int)(idx / 3200), rem = (int)(idx % 3200);
    int k = rem / NCOL, col = rem % NCOL;
    int et = col / 80, r = col % 80, mat = r / 20, d = r % 20;
    const float* w = (mat==0)?Wq:(mat==1)?Ws_:(mat==2)?Wk:Wv;
    WL[idx] = w[(((size_t)l*2 + et)*D + k)*D + d];
    return;
  }
  idx -= 9600;
  if (idx < 480) {                          // biasL: 3 x [160]
    int l = (int)(idx / NCOL), col = (int)(idx % NCOL);
    int et = col / 80, r = col % 80, mat = r / 20, d = r % 20;
    const float* b = (mat==0)?bq:(mat==1)?bs_:(mat==2)?bk:bv;
    biasL[idx] = b[(l*2 + et)*D + d];
    return;
  }
  idx -= 480;
  if (idx < 4*NBNP*40) { bnp[idx] = 0.f; return; } // BN partials: [4][64][40]
  idx -= 4*NBNP*40;
  if (idx < 2*N_NODES) { deg[idx] = 0; return; }
}

// ---------------- CSR build (XCD-partitioned) --------------------------------------------
#define SC_EPT 16
#define SC_CHUNK (256*SC_EPT)

__global__ void hist_kernel(const int* __restrict__ same, const int* __restrict__ diff,
                            int* __restrict__ deg)
{
  const int part  = blockIdx.x & 7;
  const int chunk = blockIdx.x >> 3;
  const int lo = part * (N_NODES/8);
  const int hi = lo + (N_NODES/8);
  const long i0 = (long)chunk * SC_CHUNK + threadIdx.x;
#pragma unroll
  for (int it = 0; it < SC_EPT; ++it) {
    long i = i0 + (long)it*256;
    if (i >= 2L*E_EDGES) break;
    int et = (i >= E_EDGES) ? 1 : 0;
    long e = i - (long)et*E_EDGES;
    const int* ix = et ? diff : same;
    int dst = ix[E_EDGES + e];
    if (dst >= lo && dst < hi)
      atomicAdd(&deg[(size_t)et*N_NODES + dst], 1);
  }
}

__global__ void scan_kernel(const int* __restrict__ deg,
                            int* __restrict__ rowptr0, int* __restrict__ rowptr1,
                            int* __restrict__ next0, int* __restrict__ next1)
{
  const int et = blockIdx.x;
  const int* dg = deg + (size_t)et*N_NODES;
  int* rp = et ? rowptr1 : rowptr0;
  int* np = et ? next1 : next0;
  __shared__ int part[1024];
  const int t = threadIdx.x;
  const int per = (N_NODES + 1023) / 1024;  // 49
  const int b = t * per;
  const int e = (b + per < N_NODES) ? (b + per) : N_NODES;
  int s = 0;
  for (int i = b; i < e; i++) s += dg[i];
  part[t] = s;
  __syncthreads();
  for (int o = 1; o < 1024; o <<= 1) {
    int v = (t >= o) ? part[t-o] : 0;
    __syncthreads();
    part[t] += v;
    __syncthreads();
  }
  int run = (t == 0) ? 0 : part[t-1];
  for (int i = b; i < e; i++) {
    rp[i] = run; np[i] = run;
    run += dg[i];
  }
  if (t == 0) rp[N_NODES] = part[1023];
}

__global__ void scatter_kernel(const int* __restrict__ same, const int* __restrict__ diff,
                               int* __restrict__ next0, int* __restrict__ next1,
                               int* __restrict__ adj0, int* __restrict__ adj1)
{
  const int part  = blockIdx.x & 7;
  const int chunk = blockIdx.x >> 3;
  const int lo = part * (N_NODES/8);
  const int hi = lo + (N_NODES/8);
  const long i0 = (long)chunk * SC_CHUNK + threadIdx.x;
#pragma unroll
  for (int it = 0; it < SC_EPT; ++it) {
    long i = i0 + (long)it*256;
    if (i >= 2L*E_EDGES) break;
    int et = (i >= E_EDGES) ? 1 : 0;
    long e = i - (long)et*E_EDGES;
    const int* ix = et ? diff : same;
    int dst = ix[E_EDGES + e];
    if (dst >= lo && dst < hi) {
      int src = ix[e];
      int* np  = et ? next1 : next0;
      int* adj = et ? adj1  : adj0;
      int pos = atomicAdd(&np[dst], 1);
      adj[pos] = src;
    }
  }
}

// ---------------- layer-0 MFMA GEMM: 64-row tiles, padded LDS, depth-4 prefetch ---------
__launch_bounds__(256)
__global__ void gemm0_mfma(const float* __restrict__ A,
                           const __bf16* __restrict__ Bt,
                           const float* __restrict__ bias,
                           __bf16* __restrict__ QS,
                           __bf16* __restrict__ KV0, __bf16* __restrict__ KV1)
{
  __shared__ __bf16 as[2][64*LSTR];
  const int t    = threadIdx.x;
  const int lane = t & 63;
  const int wid  = t >> 6;          // 0..3
  const int wr   = wid >> 1;        // 0..1 -> rows wr*32
  const int wc   = wid & 1;         // 0..1 -> cols wc*80
  const int rb0  = blockIdx.x * 64;

  const int srow = t >> 2;          // staging: row 0..63
  const int skc  = (t & 3) * 8;     // k chunk of 8
  const int arow = rb0 + srow;
  const float* aptr = A + (size_t)arow * F_IN;

  const int lrow = lane & 15;
  const int lkb  = (lane >> 4) * 8;

  f32x4 acc[2][5];
#pragma unroll
  for (int i = 0; i < 2; i++)
#pragma unroll
    for (int j = 0; j < 5; j++) acc[i][j] = (f32x4){0.f,0.f,0.f,0.f};

  auto loadA = [&](int k0, float4& q0, float4& q1) {
    int k = k0 + skc;
    if (arow < N_NODES) {
      if (k + 8 <= F_IN) {
        q0 = *(const float4*)(aptr + k);
        q1 = *(const float4*)(aptr + k + 4);
      } else {
        float tmp[8];
#pragma unroll
        for (int i = 0; i < 8; i++) tmp[i] = (k + i < F_IN) ? aptr[k + i] : 0.f;
        q0 = make_float4(tmp[0],tmp[1],tmp[2],tmp[3]);
        q1 = make_float4(tmp[4],tmp[5],tmp[6],tmp[7]);
      }
    } else {
      q0 = make_float4(0,0,0,0); q1 = q0;
    }
  };
  auto cvtStore = [&](int buf, const float4& q0, const float4& q1) {
    bf16x8 h;
    h[0]=(__bf16)q0.x; h[1]=(__bf16)q0.y; h[2]=(__bf16)q0.z; h[3]=(__bf16)q0.w;
    h[4]=(__bf16)q1.x; h[5]=(__bf16)q1.y; h[6]=(__bf16)q1.z; h[7]=(__bf16)q1.w;
    *(bf16x8*)&as[buf][srow*LSTR + skc] = h;
  };

  // depth-4 pipeline: r0/r1/r2 hold A-chunks for steps s+1, s+2, s+3
  float4 r0a, r0b, r1a, r1b, r2a, r2b;
  {
    float4 c0, c1;
    loadA(0, c0, c1);
    loadA(1*32, r0a, r0b);
    loadA(2*32, r1a, r1b);
    loadA(3*32, r2a, r2b);
    cvtStore(0, c0, c1);
  }
  __syncthreads();

  for (int s = 0; s < 63; s++) {
    const int cur = s & 1;
    bf16x8 af[2];
#pragma unroll
    for (int rf = 0; rf < 2; rf++)
      af[rf] = *(bf16x8*)&as[cur][(wr*32 + rf*16 + lrow)*LSTR + lkb];
    bf16x8 bfr[5];
#pragma unroll
    for (int cf = 0; cf < 5; cf++)
      bfr[cf] = *(const bf16x8*)(Bt + (size_t)(wc*80 + cf*16 + lrow)*KPAD + s*32 + lkb);

    if (s + 1 < 63) cvtStore(cur ^ 1, r0a, r0b);   // stage step s+1
    float4 na = make_float4(0,0,0,0), nb = na;
    if (s + 4 < 63) loadA((s + 4) * 32, na, nb);   // issue load for step s+4

#pragma unroll
    for (int rf = 0; rf < 2; rf++)
#pragma unroll
      for (int cf = 0; cf < 5; cf++)
        acc[rf][cf] = __builtin_amdgcn_mfma_f32_16x16x32_bf16(af[rf], bfr[cf], acc[rf][cf], 0, 0, 0);
    __syncthreads();

    r0a = r1a; r0b = r1b;
    r1a = r2a; r1b = r2b;
    r2a = na;  r2b = nb;
  }

  // epilogue: C/D layout col=lane&15, row=(lane>>4)*4 + j ; route to QS/KV
#pragma unroll
  for (int rf = 0; rf < 2; rf++) {
#pragma unroll
    for (int cf = 0; cf < 5; cf++) {
      int col = wc*80 + cf*16 + lrow;
      int et = col / 80, r = col % 80, mat = r / 20, d = r % 20;
      float bv = bias[col];
      __bf16* kvp = et ? KV1 : KV0;
#pragma unroll
      for (int j = 0; j < 4; j++) {
        int row = rb0 + wr*32 + rf*16 + (lane >> 4)*4 + j;
        if (row < N_NODES) {
          __bf16 val = (__bf16)(acc[rf][cf][j] + bv);
          if (mat < 2) QS[(size_t)row*80 + et*40 + mat*20 + d] = val;
          else         kvp[(size_t)row*64 + (mat-2)*20 + d]   = val;
        }
      }
    }
  }
}

// ---------------- layers 1..3 projection with inline BN+leakyReLU -----------------------
__launch_bounds__(256)
__global__ void proj_small_kernel(const float* __restrict__ xp, const float* __restrict__ bnl,
                                  const float* __restrict__ gam, const float* __restrict__ bet,
                                  const float* __restrict__ W, const float* __restrict__ bias,
                                  __bf16* __restrict__ QS,
                                  __bf16* __restrict__ KV0, __bf16* __restrict__ KV1)
{
  __shared__ float ws[20*160];
  __shared__ float xs[16*20];
  __shared__ float Ac[20], Bc[20];
  const int t = threadIdx.x;
  const int n0 = blockIdx.x * 16;
#pragma unroll
  for (int i = 0; i < 13; i++) {
    int idx = t + i*256;
    if (idx < 3200) ws[idx] = W[idx];
  }
  if (t < 20) {
    float s1 = 0.f, s2 = 0.f;
    for (int s = 0; s < NBNP; s++) { s1 += bnl[s*40 + t]; s2 += bnl[s*40 + 20 + t]; }
    float mu  = s1 * (1.f/N_NODES);
    float var = s2 * (1.f/N_NODES) - mu*mu;
    float a = rsqrtf(var + 1e-5f) * gam[t];
    Ac[t] = a; Bc[t] = bet[t] - mu*a;
  }
  __syncthreads();
#pragma unroll
  for (int i = 0; i < 2; i++) {
    int idx = t + i*256;
    if (idx < 320) {
      int nl = idx / 20, k = idx % 20;
      int n = n0 + nl;
      float x = (n < N_NODES) ? xp[(size_t)n*D + k] : 0.f;
      float y = x*Ac[k] + Bc[k];
      xs[idx] = (y > 0.f) ? y : 0.01f*y;
    }
  }
  __syncthreads();
#pragma unroll
  for (int i = 0; i < 10; i++) {
    int idx = t + i*256;
    int nl = idx / NCOL, col = idx % NCOL;
    int n = n0 + nl;
    if (n < N_NODES) {
      float acc = bias[col];
#pragma unroll
      for (int k = 0; k < 20; k++) acc += xs[nl*20 + k] * ws[k*NCOL + col];
      int et = col / 80, r = col % 80, mat = r / 20, d = r % 20;
      __bf16 val = (__bf16)acc;
      if (mat < 2) QS[(size_t)n*80 + et*40 + mat*20 + d] = val;
      else         (et ? KV1 : KV0)[(size_t)n*64 + (mat-2)*20 + d] = val;
    }
  }
}

// ---------------- fused attention + combine + BN partial sums ---------------------------
// 16 lanes per (node,et): wave = 2 nodes x 2 ets. Per-lane independent gathers (paired,
// 10 loads in flight). Reduction = 4 butterfly rounds over 16 lanes, serving 2 nodes/wave.
// BN partials: et0-group adds sums (lanes 0-15 -> d 0-15, lanes 0-3 also d 16-19);
// et1-group adds squared sums likewise (both groups hold identical combined x).
__launch_bounds__(256)
__global__ void attn_fused(const int* __restrict__ rp0, const int* __restrict__ adj0,
                           const int* __restrict__ rp1, const int* __restrict__ adj1,
                           const __bf16* __restrict__ QS,
                           const __bf16* __restrict__ KV0, const __bf16* __restrict__ KV1,
                           const float* __restrict__ w1, const float* __restrict__ w2, int l,
                           float* __restrict__ xpre, float* __restrict__ bnp)
{
  const int t    = threadIdx.x;
  const int wv   = t >> 6;
  const int lane = t & 63;
  const int g    = lane >> 4;         // group 0..3: (nodeA,et0)(nodeA,et1)(nodeB,et0)(nodeB,et1)
  const int sl   = lane & 15;
  const int et   = g & 1;
  const int node = blockIdx.x*8 + wv*2 + (g >> 1);   // grid = 6250 exactly

  const int* rowptr = et ? rp1 : rp0;
  const int* adj    = et ? adj1 : adj0;
  const __bf16* kvb = et ? KV1 : KV0;
  const __bf16* rq  = QS + (size_t)node*80 + et*40;   // q[0..20) s[20..40)

  float qf[20];
  {
    bf16x8 q0 = *(const bf16x8*)(rq);
    bf16x8 q1 = *(const bf16x8*)(rq + 8);
    bf16x4 q2 = *(const bf16x4*)(rq + 16);
#pragma unroll
    for (int i = 0; i < 8; i++) { qf[i] = (float)q0[i]; qf[8+i] = (float)q1[i]; }
#pragma unroll
    for (int i = 0; i < 4; i++) qf[16+i] = (float)q2[i];
  }

  const int beg = rowptr[node], end = rowptr[node+1];
  float z = 0.f;
  float S[20];
#pragma unroll
  for (int d = 0; d < 20; d++) S[d] = 0.f;

  int i = beg + sl;
  // paired loop: 2 edges (10 loads) in flight per lane
  for (; i + 16 < end; i += 32) {
    const int s0 = adj[i], s1 = adj[i+16];
    const __bf16* kva = kvb + (size_t)s0*64;
    const __bf16* kvc = kvb + (size_t)s1*64;
    bf16x8 a0 = *(const bf16x8*)(kva);
    bf16x8 a1 = *(const bf16x8*)(kva + 8);
    bf16x8 a2 = *(const bf16x8*)(kva + 16);
    bf16x8 a3 = *(const bf16x8*)(kva + 24);
    bf16x8 a4 = *(const bf16x8*)(kva + 32);
    bf16x8 b0 = *(const bf16x8*)(kvc);
    bf16x8 b1 = *(const bf16x8*)(kvc + 8);
    bf16x8 b2 = *(const bf16x8*)(kvc + 16);
    bf16x8 b3 = *(const bf16x8*)(kvc + 24);
    bf16x8 b4 = *(const bf16x8*)(kvc + 32);

    float d0 = 0.f, d1 = 0.f;
#pragma unroll
    for (int j = 0; j < 8; j++) { d0 += qf[j]*(float)a0[j];     d1 += qf[j]*(float)b0[j]; }
#pragma unroll
    for (int j = 0; j < 8; j++) { d0 += qf[8+j]*(float)a1[j];   d1 += qf[8+j]*(float)b1[j]; }
#pragma unroll
    for (int j = 0; j < 4; j++) { d0 += qf[16+j]*(float)a2[j];  d1 += qf[16+j]*(float)b2[j]; }
    const float w0 = __expf(fminf(d0*INV_SQRT_D, 80.f));
    const float w1v= __expf(fminf(d1*INV_SQRT_D, 80.f));
    z += w0 + w1v;
#pragma unroll
    for (int d = 0; d < 4; d++) S[d]     += w0*(float)a2[4+d] + w1v*(float)b2[4+d];
#pragma unroll
    for (int d = 0; d < 8; d++) S[4+d]   += w0*(float)a3[d]   + w1v*(float)b3[d];
#pragma unroll
    for (int d = 0; d < 8; d++) S[12+d]  += w0*(float)a4[d]   + w1v*(float)b4[d];
  }
  // tail: at most one edge per lane
  if (i < end) {
    const int s0 = adj[i];
    const __bf16* kva = kvb + (size_t)s0*64;
    bf16x8 a0 = *(const bf16x8*)(kva);
    bf16x8 a1 = *(const bf16x8*)(kva + 8);
    bf16x8 a2 = *(const bf16x8*)(kva + 16);
    bf16x8 a3 = *(const bf16x8*)(kva + 24);
    bf16x8 a4 = *(const bf16x8*)(kva + 32);
    float d0 = 0.f;
#pragma unroll
    for (int j = 0; j < 8; j++) d0 += qf[j]     * (float)a0[j];
#pragma unroll
    for (int j = 0; j < 8; j++) d0 += qf[8 + j] * (float)a1[j];
#pragma unroll
    for (int j = 0; j < 4; j++) d0 += qf[16 + j]* (float)a2[j];
    const float w0 = __expf(fminf(d0*INV_SQRT_D, 80.f));
    z += w0;
#pragma unroll
    for (int d = 0; d < 4; d++) S[d]     += w0*(float)a2[4+d];
#pragma unroll
    for (int d = 0; d < 8; d++) S[4+d]   += w0*(float)a3[d];
#pragma unroll
    for (int d = 0; d < 8; d++) S[12+d]  += w0*(float)a4[d];
  }

  // butterfly sum within each 16-lane group (4 rounds)
#pragma unroll
  for (int o = 8; o >= 1; o >>= 1) {
    z += __shfl_xor(z, o, 64);
#pragma unroll
    for (int d = 0; d < 20; d++) S[d] += __shfl_xor(S[d], o, 64);
  }

  // per-(node,et) output: S/z + skip (s at rq+20)
  const float inv = (z > 0.f) ? 1.f/z : 0.f;
  float outv[20];
  {
    bf16x4 s0 = *(const bf16x4*)(rq + 20);
    bf16x8 s1 = *(const bf16x8*)(rq + 24);
    bf16x8 s2 = *(const bf16x8*)(rq + 32);
#pragma unroll
    for (int i2 = 0; i2 < 4; i2++) outv[i2] = S[i2]*inv + (float)s0[i2];
#pragma unroll
    for (int i2 = 0; i2 < 8; i2++) { outv[4+i2]  = S[4+i2]*inv  + (float)s1[i2];
                                     outv[12+i2] = S[12+i2]*inv + (float)s2[i2]; }
  }

  // cross-et combine: lane ^ 16 flips et within the same node
  const float wa = w1[l], wb = w2[l];
  const float c0 = wa/(wa+wb), c1 = wb/(wa+wb);
  const float cme = et ? c1 : c0;
  const float cot = et ? c0 : c1;
  float x[20];
#pragma unroll
  for (int d = 0; d < 20; d++) {
    float o2 = __shfl_xor(outv[d], 16, 64);
    x[d] = cme*outv[d] + cot*o2;
  }

  if (et == 0 && sl == 0) {     // lanes 0 and 32 write their node's row
    float* xo = xpre + (size_t)node*D;
#pragma unroll
    for (int j = 0; j < 5; j++) {
      float4 o4 = make_float4(x[4*j], x[4*j+1], x[4*j+2], x[4*j+3]);
      *(float4*)(xo + 4*j) = o4;
    }
  }

  // BN partials: lane sl covers d=sl; lanes 0-3 also cover d=16+sl (16 lanes < 20 dims)
  float v = x[0];
#pragma unroll
  for (int d = 1; d < 16; d++) v = (sl == d) ? x[d] : v;
  float v2 = x[16];
#pragma unroll
  for (int d = 1; d < 4; d++) v2 = (sl == d) ? x[16 + d] : v2;

  float* slot = bnp + (size_t)(node & (NBNP-1))*40;
  if (et == 0) {
    atomicAdd(&slot[sl], v);
    if (sl < 4) atomicAdd(&slot[16 + sl], v2);
  } else {
    atomicAdd(&slot[20 + sl], v*v);
    if (sl < 4) atomicAdd(&slot[36 + sl], v2*v2);
  }
}

// ---------------- final: BN+lrelu (inline) on 4 layers, concat @ Wout + bout ------------
__launch_bounds__(256)
__global__ void final_kernel(const float* __restrict__ xpre4, const float* __restrict__ bnp,
                             const float* __restrict__ gam, const float* __restrict__ bet,
                             const float* __restrict__ Wout, const float* __restrict__ bout,
                             float* __restrict__ out)
{
  __shared__ float Ac[80], Bc[80], wlds[160];
  const int t = threadIdx.x;
  if (t < 80) {
    int l = t / 20, d = t % 20;
    const float* b = bnp + l*(NBNP*40);
    float s1 = 0.f, s2 = 0.f;
    for (int s = 0; s < NBNP; s++) { s1 += b[s*40 + d]; s2 += b[s*40 + 20 + d]; }
    float mu  = s1 * (1.f/N_NODES);
    float var = s2 * (1.f/N_NODES) - mu*mu;
    float a = rsqrtf(var + 1e-5f) * gam[t];
    Ac[t] = a; Bc[t] = bet[t] - mu*a;
  }
  if (t < 160) wlds[t] = Wout[t];
  __syncthreads();

  const int n = blockIdx.x*256 + t;
  if (n >= N_NODES) return;
  float a0 = bout[0], a1 = bout[1];
#pragma unroll
  for (int l = 0; l < 4; l++) {
    const float* base = xpre4 + (size_t)l*N_NODES*D + (size_t)n*D;
#pragma unroll
    for (int d = 0; d < D; d++) {
      int idx = l*20 + d;
      float y = base[d]*Ac[idx] + Bc[idx];
      y = (y > 0.f) ? y : 0.01f*y;
      a0 += y * wlds[idx*2 + 0];
      a1 += y * wlds[idx*2 + 1];
    }
  }
  out[n*2+0] = a0;
  out[n*2+1] = a1;
}

// ----------------------------------------------------------------------------------------
extern "C" void kernel_launch(void* const* d_in, const int* in_sizes, int n_in,
                              void* d_out, int out_size, void* d_ws, size_t ws_size,
                              hipStream_t stream)
{
  const float* feat = (const float*)d_in[0];
  const int*   same = (const int*)d_in[1];
  const int*   diff = (const int*)d_in[2];
  const float* W0q = (const float*)d_in[3];
  const float* b0q = (const float*)d_in[4];
  const float* W0k = (const float*)d_in[5];
  const float* b0k = (const float*)d_in[6];
  const float* W0v = (const float*)d_in[7];
  const float* b0v = (const float*)d_in[8];
  const float* W0s = (const float*)d_in[9];
  const float* b0s = (const float*)d_in[10];
  const float* Wq  = (const float*)d_in[11];
  const float* bq  = (const float*)d_in[12];
  const float* Wk  = (const float*)d_in[13];
  const float* bk  = (const float*)d_in[14];
  const float* Wv  = (const float*)d_in[15];
  const float* bv  = (const float*)d_in[16];
  const float* Ws_ = (const float*)d_in[17];
  const float* bs_ = (const float*)d_in[18];
  const float* w1  = (const float*)d_in[19];
  const float* w2  = (const float*)d_in[20];
  const float* gamma = (const float*)d_in[21];
  const float* beta  = (const float*)d_in[22];
  const float* Wout  = (const float*)d_in[23];
  const float* bout  = (const float*)d_in[24];

  float* wsf  = (float*)d_ws;
  __bf16*  QS    = (__bf16*)wsf;                 // 4,000,000 bf16 [N][80]
  __bf16*  KV0   = (__bf16*)(wsf + 2000000);     // 3,200,000 bf16 rows of 64 (128B aligned)
  __bf16*  KV1   = (__bf16*)(wsf + 3600000);
  float*   XPRE4 = wsf + 5200000;                // 4,000,000  [4][N][20] pre-BN
  __bf16*  B0bf  = (__bf16*)(wsf + 9200000);     //   322,560 bf16
  float*   BIAS0 = wsf + 9361280;                //       160
  float*   WL    = wsf + 9361440;                //     9,600
  float*   BIASL = wsf + 9371040;                //       480
  float*   BNP   = wsf + 9371520;                //    10,240  [4][64][40]
  int*     ib    = (int*)(wsf + 9381760);
  int* DEG  = ib;                                // 100,000
  int* RP0  = ib + 100000;                       //  50,004
  int* RP1  = ib + 150004;                       //  50,004
  int* NX0  = ib + 200008;                       //  50,000
  int* NX1  = ib + 250008;                       //  50,000
  int* ADJ0 = ib + 300008;                       // 1,600,000
  int* ADJ1 = ib + 1900008;                      // 1,600,000

  // pack weights + zero BN partials/degrees
  const int packN = NCOL*KPAD + 160 + 9600 + 480 + 4*NBNP*40 + 2*N_NODES;  // 443,040
  pack_kernel<<<(packN + 255)/256, 256, 0, stream>>>(
      W0q, W0k, W0v, W0s, b0q, b0k, b0v, b0s,
      Wq, Wk, Wv, Ws_, bq, bk, bv, bs_,
      B0bf, BIAS0, WL, BIASL, BNP, DEG);

  // CSR by dst, per edge type (indices identical across layers)
  const long nchunk = (2L*E_EDGES + SC_CHUNK - 1) / SC_CHUNK;
  hist_kernel<<<(int)(nchunk*8), 256, 0, stream>>>(same, diff, DEG);
  scan_kernel<<<2, 1024, 0, stream>>>(DEG, RP0, RP1, NX0, NX1);
  scatter_kernel<<<(int)(nchunk*8), 256, 0, stream>>>(same, diff, NX0, NX1, ADJ0, ADJ1);

  for (int l = 0; l < 4; l++) {
    if (l == 0)
      gemm0_mfma<<<(N_NODES + 63)/64, 256, 0, stream>>>(feat, B0bf, BIAS0, QS, KV0, KV1);
    else
      proj_small_kernel<<<(N_NODES + 15)/16, 256, 0, stream>>>(
          XPRE4 + (size_t)(l-1)*N_NODES*D, BNP + (l-1)*(NBNP*40),
          gamma + (l-1)*D, beta + (l-1)*D,
          WL + (size_t)(l-1)*3200, BIASL + (size_t)(l-1)*160, QS, KV0, KV1);

    attn_fused<<<N_NODES/8, 256, 0, stream>>>(
        RP0, ADJ0, RP1, ADJ1, QS, KV0, KV1, w1, w2, l,
        XPRE4 + (size_t)l*N_NODES*D, BNP + l*(NBNP*40));
  }

  final_kernel<<<(N_NODES + 255)/256, 256, 0, stream>>>(
      XPRE4, BNP, gamma, beta, Wout, bout, (float*)d_out);
}